// Round 1
// baseline (8821.210 us; speedup 1.0000x reference)
//
#include <hip/hip_runtime.h>
#include <stdint.h>

#define TSTEPS 500
#define NB 128
#define NH 256
#define RINGN 32

typedef _Float16 f16;
typedef _Float16 f16x8 __attribute__((ext_vector_type(8)));
typedef float f32x4 __attribute__((ext_vector_type(4)));

// ---------------- workspace layout ----------------
static constexpr size_t SZ_XCAT  = (size_t)TSTEPS*NB*256*2;      // [T][B][256] f16 (203 real + pad0)
static constexpr size_t SZ_WPACK = (size_t)6*8*128*512*2;        // [6][8][n=128][k=512] f16, swizzled image
static constexpr size_t SZ_BPACK = (size_t)6*8*128*4;            // f32 bias (forget +1 folded)
static constexpr size_t SZ_HBUF  = (size_t)6*RINGN*NB*NH*2;      // h ring [6][32][128][256] f16
static constexpr size_t SZ_FLAGS = (size_t)6*(TSTEPS+1)*4;
static constexpr size_t OFF_XCAT  = 0;
static constexpr size_t OFF_WPACK = OFF_XCAT + SZ_XCAT;
static constexpr size_t OFF_BPACK = OFF_WPACK + SZ_WPACK;
static constexpr size_t OFF_HBUF  = OFF_BPACK + SZ_BPACK;
static constexpr size_t OFF_FLAGS = OFF_HBUF + SZ_HBUF;
static constexpr size_t OFF_RNN   = (OFF_FLAGS + SZ_FLAGS + 255) & ~(size_t)255;
static constexpr size_t SZ_RNN    = (size_t)NB*512*4;            // [128][512] f32 (max over t of [hf;hb])
static constexpr size_t WS_NEED   = OFF_RNN + SZ_RNN;            // ~52 MB

// ---------------- prep: embed + concat + pad, cast f16 ----------------
__global__ void embed_kernel(const int* __restrict__ words,
                             const int* __restrict__ caps,
                             const float* __restrict__ emb,
                             const float* __restrict__ capt,
                             f16* __restrict__ xcat) {
  int t = blockIdx.x >> 7, b = blockIdx.x & 127, k = threadIdx.x;
  int w  = words[b*TSTEPS + t];
  int cp = caps [b*TSTEPS + t];
  float v = 0.f;
  if (k < 200)      v = emb[(size_t)w*200 + k];
  else if (k < 203) v = capt[cp*3 + (k-200)];
  xcat[((size_t)t*NB + b)*256 + k] = (f16)v;
}

// ---------------- prep: pack weights per (layer,wg) ----------------
// LDS image: column-major per n (k contiguous), 16B-block XOR swizzle:
//   elem(n,k) -> n*512 + (((k>>3) ^ (n&7))<<3) + (k&7)
// n (0..127): nt=n>>4, gate=nt>>1, unit = wg*32 + (nt&1)*16 + (n&15)
// k (0..511): k<256 = input rows (layer0: xcat rows 0..202, else h^{l-1}); k>=256 = own-h rows
__global__ void pack_kernel(const float* __restrict__ Wf0, const float* __restrict__ bf0,
                            const float* __restrict__ Wf1, const float* __restrict__ bf1,
                            const float* __restrict__ Wf2, const float* __restrict__ bf2,
                            const float* __restrict__ Wb0, const float* __restrict__ bb0,
                            const float* __restrict__ Wb1, const float* __restrict__ bb1,
                            const float* __restrict__ Wb2, const float* __restrict__ bb2,
                            f16* __restrict__ wpack, float* __restrict__ bpack) {
  int bid = blockIdx.x;
  int n = bid & 127, wg = (bid >> 7) & 7, layer = bid >> 10;
  const float* W; const float* bb;
  switch (layer) {
    case 0: W = Wf0; bb = bf0; break;
    case 1: W = Wf1; bb = bf1; break;
    case 2: W = Wf2; bb = bf2; break;
    case 3: W = Wb0; bb = bb0; break;
    case 4: W = Wb1; bb = bb1; break;
    default: W = Wb2; bb = bb2; break;
  }
  int level = layer % 3;
  int nt = n >> 4, c = n & 15;
  int gate = nt >> 1;
  int col = gate*256 + wg*32 + (nt & 1)*16 + c;   // column in original [.,1024] W
  if (threadIdx.x == 0)
    bpack[((layer*8 + wg) << 7) + n] = bb[col] + (gate == 2 ? 1.f : 0.f); // fold forget_bias
  size_t base = ((size_t)(layer*8 + wg)*128 + n)*512;
  for (int k = threadIdx.x; k < 512; k += 256) {
    int row;
    if (level == 0) row = (k < 203) ? k : ((k < 256) ? -1 : k - 53);  // -53: 256->203
    else            row = k;
    float v = (row < 0) ? 0.f : W[(size_t)row*1024 + col];
    int idx = (((k >> 3) ^ (n & 7)) << 3) + (k & 7);
    wpack[base + idx] = (f16)v;
  }
}

// ---------------- prep: flags + ring slot0 = h_0 = 0 ----------------
__global__ void init_kernel(int* __restrict__ flags, f16* __restrict__ hbuf) {
  int i = blockIdx.x*256 + threadIdx.x;
  if (i < 6*(TSTEPS+1)) flags[i] = ((i % (TSTEPS+1)) == 0) ? 8 : 0;
  if (i < 6*16384) {
    int l = i >> 14, e = i & 16383;
    ((unsigned int*)(hbuf + (size_t)l*RINGN*NB*NH))[e] = 0u;
  }
}

// ---------------- pipelined persistent LSTM ----------------
__device__ __forceinline__ void spin_ge8(int* p) {
  while (__hip_atomic_load(p, __ATOMIC_RELAXED, __HIP_MEMORY_SCOPE_AGENT) < 8)
    __builtin_amdgcn_s_sleep(1);
}
__device__ __forceinline__ float sigf(float x) { return 1.f/(1.f + __expf(-x)); }
__device__ __forceinline__ float tanhf_(float x) {
  float e = __expf(-2.f*fabsf(x));
  float r = (1.f - e)/(1.f + e);
  return x < 0.f ? -r : r;
}

// grid = 48 (6 layers x 8 WGs), block = 256 (4 waves), dynLDS = 128KB weights
// wave wv: mhalf=wv>>1 -> rows [mhalf*64, +64); npar=wv&1 -> N-tiles {npar,2+npar,4+npar,6+npar}
// so each lane's 4 acc frags are gates i,j,f,o of ONE hidden unit (no cross-lane for the cell update).
__global__ __launch_bounds__(256, 1)
void lstm_pipeline(const f16* __restrict__ xcat, const f16* __restrict__ wpack,
                   const float* __restrict__ bpack, f16* __restrict__ hbuf,
                   int* __restrict__ flags, float* __restrict__ rnn_out) {
  extern __shared__ char smem[];
  const int layer = blockIdx.x >> 3, wg = blockIdx.x & 7;
  const int stack = layer/3, level = layer - stack*3;

  { // weights -> LDS (swizzled image, linear copy)
    const uint4* src = (const uint4*)(wpack + (size_t)(layer*8 + wg)*128*512);
    uint4* dst = (uint4*)smem;
    for (int i = threadIdx.x; i < 8192; i += 256) dst[i] = src[i];
  }
  const int lane = threadIdx.x & 63, wv = threadIdx.x >> 6;
  const int lc = lane & 15, akg = lane >> 4;
  const int mhalf = wv >> 1, npar = wv & 1;

  float bI, bJ, bF, bO;
  {
    const float* bb = bpack + ((size_t)(layer*8 + wg) << 7);
    bI = bb[(0*2 + npar)*16 + lc];
    bJ = bb[(1*2 + npar)*16 + lc];
    bF = bb[(2*2 + npar)*16 + lc];
    bO = bb[(3*2 + npar)*16 + lc];
  }
  __syncthreads();

  const size_t aoff = (size_t)(mhalf*64 + lc)*256 + akg*8;   // A frag: row=lane&15(+16*mt), k=8*(lane>>4)
  const int boff0 = ((0*2 + npar)*16 + lc)*1024;             // B frag: col=lane&15, k=8*(lane>>4)
  const int boff1 = ((1*2 + npar)*16 + lc)*1024;
  const int boff2 = ((2*2 + npar)*16 + lc)*1024;
  const int boff3 = ((3*2 + npar)*16 + lc)*1024;
  const int bx = lc & 7;
  const int rowbase = mhalf*64 + akg*4;                      // C/D: row=(lane>>4)*4+reg (+16*mt)
  const int ucol = wg*32 + npar*16 + lc;                     // this lane's hidden unit

  int* fl_own  = flags + layer*(TSTEPS+1);
  int* fl_prev = flags + (layer-1)*(TSTEPS+1);
  int* fl_next = flags + (layer+1)*(TSTEPS+1);

  float c_st[4][4];
  float hmx[4][4];
  #pragma unroll
  for (int a = 0; a < 4; ++a)
    #pragma unroll
    for (int b = 0; b < 4; ++b) { c_st[a][b] = 0.f; hmx[a][b] = -2.f; }

  for (int t = 1; t <= TSTEPS; ++t) {
    spin_ge8(fl_own + (t-1));                          // own h_{t-1} complete (all 8 WGs)
    if (level) spin_ge8(fl_prev + t);                  // input h^{l-1}_t ready
    if (level < 2 && t > RINGN) spin_ge8(fl_next + (t - RINGN));   // ring back-pressure
    __builtin_amdgcn_fence(__ATOMIC_ACQUIRE, "agent");

    const f16* Ain = level ? (hbuf + ((size_t)(layer-1)*RINGN + (size_t)(t & (RINGN-1)))*NB*NH)
                           : (xcat + (size_t)(stack ? (TSTEPS - t) : (t-1))*NB*256);
    const f16* Ah  = hbuf + ((size_t)layer*RINGN + (size_t)((t-1) & (RINGN-1)))*NB*NH;

    f32x4 acc[4][4];
    #pragma unroll
    for (int a = 0; a < 4; ++a)
      #pragma unroll
      for (int g = 0; g < 4; ++g) acc[a][g] = (f32x4){0.f,0.f,0.f,0.f};

#define GEMM_HALF(BASE, KC0)                                                        \
    _Pragma("unroll")                                                               \
    for (int k8 = 0; k8 < 8; ++k8) {                                                \
      f16x8 a0 = *(const f16x8*)((BASE) + aoff + k8*32);                            \
      f16x8 a1 = *(const f16x8*)((BASE) + aoff + k8*32 + 16*256);                   \
      f16x8 a2 = *(const f16x8*)((BASE) + aoff + k8*32 + 32*256);                   \
      f16x8 a3 = *(const f16x8*)((BASE) + aoff + k8*32 + 48*256);                   \
      int swz = ((((KC0) + k8)*4 + akg) ^ bx) << 4;                                 \
      f16x8 vb0 = *(const f16x8*)(smem + boff0 + swz);                              \
      f16x8 vb1 = *(const f16x8*)(smem + boff1 + swz);                              \
      f16x8 vb2 = *(const f16x8*)(smem + boff2 + swz);                              \
      f16x8 vb3 = *(const f16x8*)(smem + boff3 + swz);                              \
      acc[0][0] = __builtin_amdgcn_mfma_f32_16x16x32_f16(a0, vb0, acc[0][0],0,0,0); \
      acc[0][1] = __builtin_amdgcn_mfma_f32_16x16x32_f16(a0, vb1, acc[0][1],0,0,0); \
      acc[0][2] = __builtin_amdgcn_mfma_f32_16x16x32_f16(a0, vb2, acc[0][2],0,0,0); \
      acc[0][3] = __builtin_amdgcn_mfma_f32_16x16x32_f16(a0, vb3, acc[0][3],0,0,0); \
      acc[1][0] = __builtin_amdgcn_mfma_f32_16x16x32_f16(a1, vb0, acc[1][0],0,0,0); \
      acc[1][1] = __builtin_amdgcn_mfma_f32_16x16x32_f16(a1, vb1, acc[1][1],0,0,0); \
      acc[1][2] = __builtin_amdgcn_mfma_f32_16x16x32_f16(a1, vb2, acc[1][2],0,0,0); \
      acc[1][3] = __builtin_amdgcn_mfma_f32_16x16x32_f16(a1, vb3, acc[1][3],0,0,0); \
      acc[2][0] = __builtin_amdgcn_mfma_f32_16x16x32_f16(a2, vb0, acc[2][0],0,0,0); \
      acc[2][1] = __builtin_amdgcn_mfma_f32_16x16x32_f16(a2, vb1, acc[2][1],0,0,0); \
      acc[2][2] = __builtin_amdgcn_mfma_f32_16x16x32_f16(a2, vb2, acc[2][2],0,0,0); \
      acc[2][3] = __builtin_amdgcn_mfma_f32_16x16x32_f16(a2, vb3, acc[2][3],0,0,0); \
      acc[3][0] = __builtin_amdgcn_mfma_f32_16x16x32_f16(a3, vb0, acc[3][0],0,0,0); \
      acc[3][1] = __builtin_amdgcn_mfma_f32_16x16x32_f16(a3, vb1, acc[3][1],0,0,0); \
      acc[3][2] = __builtin_amdgcn_mfma_f32_16x16x32_f16(a3, vb2, acc[3][2],0,0,0); \
      acc[3][3] = __builtin_amdgcn_mfma_f32_16x16x32_f16(a3, vb3, acc[3][3],0,0,0); \
    }
    GEMM_HALF(Ain, 0)
    GEMM_HALF(Ah, 8)
#undef GEMM_HALF

    f16* hout = hbuf + ((size_t)layer*RINGN + (size_t)(t & (RINGN-1)))*NB*NH;
    #pragma unroll
    for (int mt = 0; mt < 4; ++mt) {
      #pragma unroll
      for (int r = 0; r < 4; ++r) {
        float zi = acc[mt][0][r] + bI;
        float zj = acc[mt][1][r] + bJ;
        float zf = acc[mt][2][r] + bF;   // +1 already folded
        float zo = acc[mt][3][r] + bO;
        float cs = sigf(zf)*c_st[mt][r] + sigf(zi)*tanhf_(zj);
        c_st[mt][r] = cs;
        float h = sigf(zo)*tanhf_(cs);
        hout[(size_t)(rowbase + mt*16 + r)*NH + ucol] = (f16)h;
        if (level == 2) hmx[mt][r] = fmaxf(hmx[mt][r], h);
      }
    }
    __builtin_amdgcn_fence(__ATOMIC_RELEASE, "agent");  // per-wave vmcnt drain + L2 wb
    __syncthreads();
    if (threadIdx.x == 0)
      __hip_atomic_fetch_add(fl_own + t, 1, __ATOMIC_RELAXED, __HIP_MEMORY_SCOPE_AGENT);
  }

  if (level == 2) {
    #pragma unroll
    for (int mt = 0; mt < 4; ++mt)
      #pragma unroll
      for (int r = 0; r < 4; ++r)
        rnn_out[(size_t)(rowbase + mt*16 + r)*512 + stack*256 + ucol] = hmx[mt][r];
  }
}

// ---------------- epilogue: elu(rnn@W1+b1)@W2+b2 -> sigmoid ----------------
__global__ __launch_bounds__(256)
void dense_kernel(const float* __restrict__ rnn, const float* __restrict__ W1,
                  const float* __restrict__ b1, const float* __restrict__ W2,
                  const float* __restrict__ b2, float* __restrict__ out) {
  __shared__ float h1[16][64];
  int r0 = blockIdx.x*16;
  int c = threadIdx.x & 63, rr = threadIdx.x >> 6;
  #pragma unroll
  for (int m = 0; m < 4; ++m) {
    int rl = rr*4 + m;
    const float* rp = rnn + (size_t)(r0 + rl)*512;
    float s = b1[c];
    for (int k = 0; k < 512; ++k) s = fmaf(rp[k], W1[(size_t)k*64 + c], s);
    h1[rl][c] = (s > 0.f) ? s : (__expf(s) - 1.f);
  }
  __syncthreads();
  if (threadIdx.x < 96) {
    int rl = threadIdx.x/6, cc = threadIdx.x - rl*6;
    float s = b2[cc];
    #pragma unroll
    for (int k = 0; k < 64; ++k) s = fmaf(h1[rl][k], W2[k*6 + cc], s);
    out[(size_t)(r0 + rl)*6 + cc] = 1.f/(1.f + __expf(-s));
  }
}

// ---------------- launch ----------------
extern "C" void kernel_launch(void* const* d_in, const int* in_sizes, int n_in,
                              void* d_out, int out_size, void* d_ws, size_t ws_size,
                              hipStream_t stream) {
  if (ws_size < WS_NEED) return;  // clean failure (output stays poisoned) instead of corruption
  const int*   words = (const int*)d_in[0];
  const int*   caps  = (const int*)d_in[1];
  const float* emb   = (const float*)d_in[2];
  const float* capt  = (const float*)d_in[3];
  char* ws = (char*)d_ws;
  f16*   xcat  = (f16*)  (ws + OFF_XCAT);
  f16*   wpack = (f16*)  (ws + OFF_WPACK);
  float* bpack = (float*)(ws + OFF_BPACK);
  f16*   hbuf  = (f16*)  (ws + OFF_HBUF);
  int*   flags = (int*)  (ws + OFF_FLAGS);
  float* rnn   = (float*)(ws + OFF_RNN);

  embed_kernel<<<TSTEPS*NB, 256, 0, stream>>>(words, caps, emb, capt, xcat);
  pack_kernel<<<6*8*128, 256, 0, stream>>>(
      (const float*)d_in[4],  (const float*)d_in[5],  (const float*)d_in[6],  (const float*)d_in[7],
      (const float*)d_in[8],  (const float*)d_in[9],  (const float*)d_in[10], (const float*)d_in[11],
      (const float*)d_in[12], (const float*)d_in[13], (const float*)d_in[14], (const float*)d_in[15],
      wpack, bpack);
  init_kernel<<<384, 256, 0, stream>>>(flags, hbuf);
  lstm_pipeline<<<48, 256, 131072, stream>>>(xcat, wpack, bpack, hbuf, flags, rnn);
  dense_kernel<<<8, 256, 0, stream>>>(rnn, (const float*)d_in[16], (const float*)d_in[17],
                                      (const float*)d_in[18], (const float*)d_in[19], (float*)d_out);
}

// Round 2
// 6927.762 us; speedup vs baseline: 1.2733x; 1.2733x over previous
//
#include <hip/hip_runtime.h>
#include <stdint.h>

#define TSTEPS 500
#define NB 128
#define NH 256
#define RINGN 32

typedef _Float16 f16;
typedef _Float16 f16x8 __attribute__((ext_vector_type(8)));
typedef float f32x4 __attribute__((ext_vector_type(4)));
typedef unsigned long long u64;
typedef unsigned int u32;

// ---------------- workspace layout ----------------
static constexpr size_t SZ_XCAT  = (size_t)TSTEPS*NB*256*2;      // [T][B][256] f16 (203 real + pad0)
static constexpr size_t SZ_WPACK = (size_t)6*8*128*512*2;        // [6][8][n=128][k=512] f16, swizzled image
static constexpr size_t SZ_BPACK = (size_t)6*8*128*4;            // f32 bias (forget +1 folded)
static constexpr size_t SZ_HBUF  = (size_t)6*RINGN*NB*NH*2;      // h ring [6][32][128][256] f16
static constexpr size_t SZ_FLAGS = (size_t)6*(TSTEPS+1)*8*4;     // per-WG flag slots
static constexpr size_t OFF_XCAT  = 0;
static constexpr size_t OFF_WPACK = OFF_XCAT + SZ_XCAT;
static constexpr size_t OFF_BPACK = OFF_WPACK + SZ_WPACK;
static constexpr size_t OFF_HBUF  = OFF_BPACK + SZ_BPACK;
static constexpr size_t OFF_FLAGS = OFF_HBUF + SZ_HBUF;
static constexpr size_t OFF_RNN   = (OFF_FLAGS + SZ_FLAGS + 255) & ~(size_t)255;
static constexpr size_t SZ_RNN    = (size_t)NB*512*4;            // [128][512] f32 (max over t of [hf;hb])
static constexpr size_t WS_NEED   = OFF_RNN + SZ_RNN;

// ---------------- prep: embed + concat + pad, cast f16 ----------------
__global__ void embed_kernel(const int* __restrict__ words,
                             const int* __restrict__ caps,
                             const float* __restrict__ emb,
                             const float* __restrict__ capt,
                             f16* __restrict__ xcat) {
  int t = blockIdx.x >> 7, b = blockIdx.x & 127, k = threadIdx.x;
  int w  = words[b*TSTEPS + t];
  int cp = caps [b*TSTEPS + t];
  float v = 0.f;
  if (k < 200)      v = emb[(size_t)w*200 + k];
  else if (k < 203) v = capt[cp*3 + (k-200)];
  xcat[((size_t)t*NB + b)*256 + k] = (f16)v;
}

// ---------------- prep: pack weights per (layer,wg) ----------------
// LDS image: column-major per n (k contiguous), 16B-block XOR swizzle:
//   elem(n,k) -> n*512 + (((k>>3) ^ (n&7))<<3) + (k&7)
// n (0..127): nt=n>>4 (gate=nt>>1, np=nt&1), lcn=n&15 -> unit = wg*32 + 2*lcn + np
//   (pairing units 2lc/2lc+1 per lane makes h stores lane-local u32 pairs)
// k (0..511): k<256 = input rows (layer0: xcat rows 0..202, else h^{l-1}); k>=256 = own-h rows
__global__ void pack_kernel(const float* __restrict__ Wf0, const float* __restrict__ bf0,
                            const float* __restrict__ Wf1, const float* __restrict__ bf1,
                            const float* __restrict__ Wf2, const float* __restrict__ bf2,
                            const float* __restrict__ Wb0, const float* __restrict__ bb0,
                            const float* __restrict__ Wb1, const float* __restrict__ bb1,
                            const float* __restrict__ Wb2, const float* __restrict__ bb2,
                            f16* __restrict__ wpack, float* __restrict__ bpack) {
  int bid = blockIdx.x;
  int n = bid & 127, wg = (bid >> 7) & 7, layer = bid >> 10;
  const float* W; const float* bb;
  switch (layer) {
    case 0: W = Wf0; bb = bf0; break;
    case 1: W = Wf1; bb = bf1; break;
    case 2: W = Wf2; bb = bf2; break;
    case 3: W = Wb0; bb = bb0; break;
    case 4: W = Wb1; bb = bb1; break;
    default: W = Wb2; bb = bb2; break;
  }
  int level = layer % 3;
  int nt = n >> 4, lcn = n & 15;
  int gate = nt >> 1, np = nt & 1;
  int col = gate*256 + wg*32 + 2*lcn + np;        // column in original [.,1024] W
  if (threadIdx.x == 0)
    bpack[((layer*8 + wg) << 7) + n] = bb[col] + (gate == 2 ? 1.f : 0.f); // fold forget_bias
  size_t base = ((size_t)(layer*8 + wg)*128 + n)*512;
  for (int k = threadIdx.x; k < 512; k += 256) {
    int row;
    if (level == 0) row = (k < 203) ? k : ((k < 256) ? -1 : k - 53);  // -53: 256->203
    else            row = k;
    float v = (row < 0) ? 0.f : W[(size_t)row*1024 + col];
    int idx = (((k >> 3) ^ (n & 7)) << 3) + (k & 7);
    wpack[base + idx] = (f16)v;
  }
}

// ---------------- prep: flags + ring slot0 = h_0 = 0 ----------------
__global__ void init_kernel(int* __restrict__ flags, f16* __restrict__ hbuf) {
  int i = blockIdx.x*256 + threadIdx.x;
  if (i < 6*(TSTEPS+1)*8) {
    int r = i % ((TSTEPS+1)*8);
    flags[i] = (r < 8) ? 1 : 0;                    // t=0 ready for all layers/WGs
  }
  if (i < 6*16384) {
    int l = i >> 14, e = i & 16383;
    ((unsigned int*)(hbuf + (size_t)l*RINGN*NB*NH))[e] = 0u;
  }
}

// ---------------- helpers ----------------
__device__ __forceinline__ void spin_all8(const int* p, int lane) {
  const int* q = p + (lane & 7);
  for (;;) {
    int v = __hip_atomic_load(q, __ATOMIC_RELAXED, __HIP_MEMORY_SCOPE_AGENT);
    if (__all(v != 0)) break;
    __builtin_amdgcn_s_sleep(1);
  }
}
__device__ __forceinline__ f16x8 ldA_coh(const f16* p) {   // 16B coherent (LLC) load as 2x u64
  union { u64 q[2]; f16x8 v; } u;
  u.q[0] = __hip_atomic_load((const u64*)p,     __ATOMIC_RELAXED, __HIP_MEMORY_SCOPE_AGENT);
  u.q[1] = __hip_atomic_load((const u64*)p + 1, __ATOMIC_RELAXED, __HIP_MEMORY_SCOPE_AGENT);
  return u.v;
}
__device__ __forceinline__ u32 packh2(float a, float b) {
  union { f16 h[2]; u32 u; } x;
  x.h[0] = (f16)a; x.h[1] = (f16)b;
  return x.u;
}
__device__ __forceinline__ float sigf(float x) { return 1.f/(1.f + __expf(-x)); }
__device__ __forceinline__ float tanhf_(float x) {
  float e = __expf(-2.f*fabsf(x));
  float r = (1.f - e)/(1.f + e);
  return x < 0.f ? -r : r;
}

// grid = 48 (6 layers x 8 WGs), block = 256 (4 waves), dynLDS = 128KB weights
// wave wv owns rows [wv*32, wv*32+32) x ALL 128 gate-cols (no A duplication across waves).
// Lane holds gates i,j,f,o for units (2*lc, 2*lc+1): cell update lane-local, h as u32 pair store.
__global__ __launch_bounds__(256, 1)
void lstm_pipeline(const f16* __restrict__ xcat, const f16* __restrict__ wpack,
                   const float* __restrict__ bpack, f16* __restrict__ hbuf,
                   int* __restrict__ flags, float* __restrict__ rnn_out) {
  extern __shared__ char smem[];
  const int layer = blockIdx.x >> 3, wg = blockIdx.x & 7;
  const int stack = layer/3, level = layer - stack*3;

  { // weights -> LDS (swizzled image, linear copy)
    const uint4* src = (const uint4*)(wpack + (size_t)(layer*8 + wg)*128*512);
    uint4* dst = (uint4*)smem;
    for (int i = threadIdx.x; i < 8192; i += 256) dst[i] = src[i];
  }
  const int lane = threadIdx.x & 63, wv = threadIdx.x >> 6;
  const int lc = lane & 15, akg = lane >> 4;
  const int bx = lc & 7;

  float bI[2], bJ[2], bF[2], bO[2];
  {
    const float* bb = bpack + ((size_t)(layer*8 + wg) << 7);
    #pragma unroll
    for (int np = 0; np < 2; ++np) {
      bI[np] = bb[(0*2 + np)*16 + lc];
      bJ[np] = bb[(1*2 + np)*16 + lc];
      bF[np] = bb[(2*2 + np)*16 + lc];
      bO[np] = bb[(3*2 + np)*16 + lc];
    }
  }
  __syncthreads();

  const size_t aoffL = ((size_t)(wv*32 + lc))*256 + akg*8;   // A frag: row=lane&15 (+16*mt), k=8*(lane>>4)
  int*       fl_own  = flags + layer*(TSTEPS+1)*8;
  const int* fl_prev = flags + (layer-1)*(TSTEPS+1)*8;
  const int* fl_next = flags + (layer+1)*(TSTEPS+1)*8;

  float c_st[2][2][4];
  float hmx[2][2][4];
  #pragma unroll
  for (int mt = 0; mt < 2; ++mt)
    #pragma unroll
    for (int np = 0; np < 2; ++np)
      #pragma unroll
      for (int r = 0; r < 4; ++r) { c_st[mt][np][r] = 0.f; hmx[mt][np][r] = -2.f; }

  for (int t = 1; t <= TSTEPS; ++t) {
    spin_all8(fl_own + (t-1)*8, lane);                         // own h_{t-1} complete (all 8 WGs)
    if (level) spin_all8(fl_prev + t*8, lane);                 // input h^{l-1}_t ready
    if (level < 2 && t > RINGN) spin_all8(fl_next + (t - RINGN)*8, lane);  // ring back-pressure
    __builtin_amdgcn_sched_barrier(0);
    asm volatile("" ::: "memory");

    const f16* Ain = level ? (hbuf + ((size_t)(layer-1)*RINGN + (size_t)(t & (RINGN-1)))*NB*NH)
                           : (xcat + (size_t)(stack ? (TSTEPS - t) : (t-1))*NB*256);
    const f16* Ah  = hbuf + ((size_t)layer*RINGN + (size_t)((t-1) & (RINGN-1)))*NB*NH;

    // ---- cluster ALL global A loads up front (single LLC round trip) ----
    f16x8 aI0[8], aI1[8], aH0[8], aH1[8];
    if (level == 0) {
      #pragma unroll
      for (int k8 = 0; k8 < 8; ++k8) {           // xcat immutable -> cached loads
        aI0[k8] = *(const f16x8*)(Ain + aoffL + k8*32);
        aI1[k8] = *(const f16x8*)(Ain + aoffL + 16*256 + k8*32);
      }
    } else {
      #pragma unroll
      for (int k8 = 0; k8 < 8; ++k8) {
        aI0[k8] = ldA_coh(Ain + aoffL + k8*32);
        aI1[k8] = ldA_coh(Ain + aoffL + 16*256 + k8*32);
      }
    }
    #pragma unroll
    for (int k8 = 0; k8 < 8; ++k8) {
      aH0[k8] = ldA_coh(Ah + aoffL + k8*32);
      aH1[k8] = ldA_coh(Ah + aoffL + 16*256 + k8*32);
    }

    f32x4 acc[2][8];
    #pragma unroll
    for (int mt = 0; mt < 2; ++mt)
      #pragma unroll
      for (int nt = 0; nt < 8; ++nt) acc[mt][nt] = (f32x4){0.f,0.f,0.f,0.f};

    #pragma unroll
    for (int k8 = 0; k8 < 8; ++k8) {
      const int swz0 = ((k8*4 + akg) ^ bx) << 4;          // input half   (kword 0..31)
      const int swz1 = ((32 + k8*4 + akg) ^ bx) << 4;     // recurrent half (kword 32..63)
      #pragma unroll
      for (int nt = 0; nt < 8; ++nt) {
        const char* base = smem + (nt*16 + lc)*1024;
        f16x8 vb0 = *(const f16x8*)(base + swz0);
        f16x8 vb1 = *(const f16x8*)(base + swz1);
        acc[0][nt] = __builtin_amdgcn_mfma_f32_16x16x32_f16(aI0[k8], vb0, acc[0][nt], 0,0,0);
        acc[1][nt] = __builtin_amdgcn_mfma_f32_16x16x32_f16(aI1[k8], vb0, acc[1][nt], 0,0,0);
        acc[0][nt] = __builtin_amdgcn_mfma_f32_16x16x32_f16(aH0[k8], vb1, acc[0][nt], 0,0,0);
        acc[1][nt] = __builtin_amdgcn_mfma_f32_16x16x32_f16(aH1[k8], vb1, acc[1][nt], 0,0,0);
      }
    }

    // ---- cell update (lane-local) + coherent h store as u32 unit-pairs ----
    u32* hout32 = (u32*)(hbuf + ((size_t)layer*RINGN + (size_t)(t & (RINGN-1)))*NB*NH);
    #pragma unroll
    for (int mt = 0; mt < 2; ++mt) {
      #pragma unroll
      for (int r = 0; r < 4; ++r) {
        int row = wv*32 + mt*16 + akg*4 + r;               // C/D: row=(lane>>4)*4+reg (+16*mt)
        float hv[2];
        #pragma unroll
        for (int np = 0; np < 2; ++np) {
          float zi = acc[mt][0 + np][r] + bI[np];
          float zj = acc[mt][2 + np][r] + bJ[np];
          float zf = acc[mt][4 + np][r] + bF[np];          // +1 already folded
          float zo = acc[mt][6 + np][r] + bO[np];
          float cs = sigf(zf)*c_st[mt][np][r] + sigf(zi)*tanhf_(zj);
          c_st[mt][np][r] = cs;
          float h = sigf(zo)*tanhf_(cs);
          hv[np] = h;
          if (level == 2) hmx[mt][np][r] = fmaxf(hmx[mt][np][r], h);
        }
        __hip_atomic_store(&hout32[(size_t)row*128 + wg*16 + lc], packh2(hv[0], hv[1]),
                           __ATOMIC_RELAXED, __HIP_MEMORY_SCOPE_AGENT);
      }
    }
    asm volatile("s_waitcnt vmcnt(0)" ::: "memory");        // h stores acked at LLC
    __syncthreads();                                        // all 4 waves drained
    if (threadIdx.x == 0)
      __hip_atomic_store(&fl_own[t*8 + wg], t, __ATOMIC_RELAXED, __HIP_MEMORY_SCOPE_AGENT);
  }

  if (level == 2) {
    #pragma unroll
    for (int mt = 0; mt < 2; ++mt)
      #pragma unroll
      for (int r = 0; r < 4; ++r)
        #pragma unroll
        for (int np = 0; np < 2; ++np)
          rnn_out[(size_t)(wv*32 + mt*16 + akg*4 + r)*512 + stack*256 + wg*32 + 2*lc + np]
              = hmx[mt][np][r];
  }
}

// ---------------- epilogue: elu(rnn@W1+b1)@W2+b2 -> sigmoid ----------------
__global__ __launch_bounds__(256)
void dense_kernel(const float* __restrict__ rnn, const float* __restrict__ W1,
                  const float* __restrict__ b1, const float* __restrict__ W2,
                  const float* __restrict__ b2, float* __restrict__ out) {
  __shared__ float h1[16][64];
  int r0 = blockIdx.x*16;
  int c = threadIdx.x & 63, rr = threadIdx.x >> 6;
  #pragma unroll
  for (int m = 0; m < 4; ++m) {
    int rl = rr*4 + m;
    const float* rp = rnn + (size_t)(r0 + rl)*512;
    float s = b1[c];
    for (int k = 0; k < 512; ++k) s = fmaf(rp[k], W1[(size_t)k*64 + c], s);
    h1[rl][c] = (s > 0.f) ? s : (__expf(s) - 1.f);
  }
  __syncthreads();
  if (threadIdx.x < 96) {
    int rl = threadIdx.x/6, cc = threadIdx.x - rl*6;
    float s = b2[cc];
    #pragma unroll
    for (int k = 0; k < 64; ++k) s = fmaf(h1[rl][k], W2[k*6 + cc], s);
    out[(size_t)(r0 + rl)*6 + cc] = 1.f/(1.f + __expf(-s));
  }
}

// ---------------- launch ----------------
extern "C" void kernel_launch(void* const* d_in, const int* in_sizes, int n_in,
                              void* d_out, int out_size, void* d_ws, size_t ws_size,
                              hipStream_t stream) {
  if (ws_size < WS_NEED) return;  // clean failure instead of corruption
  const int*   words = (const int*)d_in[0];
  const int*   caps  = (const int*)d_in[1];
  const float* emb   = (const float*)d_in[2];
  const float* capt  = (const float*)d_in[3];
  char* ws = (char*)d_ws;
  f16*   xcat  = (f16*)  (ws + OFF_XCAT);
  f16*   wpack = (f16*)  (ws + OFF_WPACK);
  float* bpack = (float*)(ws + OFF_BPACK);
  f16*   hbuf  = (f16*)  (ws + OFF_HBUF);
  int*   flags = (int*)  (ws + OFF_FLAGS);
  float* rnn   = (float*)(ws + OFF_RNN);

  embed_kernel<<<TSTEPS*NB, 256, 0, stream>>>(words, caps, emb, capt, xcat);
  pack_kernel<<<6*8*128, 256, 0, stream>>>(
      (const float*)d_in[4],  (const float*)d_in[5],  (const float*)d_in[6],  (const float*)d_in[7],
      (const float*)d_in[8],  (const float*)d_in[9],  (const float*)d_in[10], (const float*)d_in[11],
      (const float*)d_in[12], (const float*)d_in[13], (const float*)d_in[14], (const float*)d_in[15],
      wpack, bpack);
  init_kernel<<<384, 256, 0, stream>>>(flags, hbuf);
  lstm_pipeline<<<48, 256, 131072, stream>>>(xcat, wpack, bpack, hbuf, flags, rnn);
  dense_kernel<<<8, 256, 0, stream>>>(rnn, (const float*)d_in[16], (const float*)d_in[17],
                                      (const float*)d_in[18], (const float*)d_in[19], (float*)d_out);
}